// Round 4
// baseline (2613.521 us; speedup 1.0000x reference)
//
#include <hip/hip_runtime.h>

#define HID 768
#define WPB 16     // words per tile
#define ROWS 64    // subword rows per tile
#define BK 64      // K-chunk width
#define NCH 12     // 768 / 64 K-chunks

typedef __attribute__((ext_vector_type(4))) float f32x4;
typedef __attribute__((ext_vector_type(8))) short s16x8;

__device__ inline short f2bf(float f) {
  unsigned u = __builtin_bit_cast(unsigned, f);
  u = (u + 0x7fffu + ((u >> 16) & 1u)) >> 16;
  return (short)(unsigned short)u;
}
__device__ inline float fast_tanh(float v) {
  float e = exp2f(v * 2.885390081777927f);   // e^{2v}
  return 1.0f - 2.0f * __builtin_amdgcn_rcpf(e + 1.0f);
}
__device__ inline s16x8 pack8(f32x4 f0, f32x4 f1) {
  s16x8 p;
  p[0]=f2bf(f0[0]); p[1]=f2bf(f0[1]); p[2]=f2bf(f0[2]); p[3]=f2bf(f0[3]);
  p[4]=f2bf(f1[0]); p[5]=f2bf(f1[1]); p[6]=f2bf(f1[2]); p[7]=f2bf(f1[3]);
  return p;
}

// ---- pre-pass: W fp32 -> bf16 in workspace (L2-resident B operand) ----
__global__ void wconv_kernel(const float* __restrict__ W, short* __restrict__ Wb, int n8) {
  int i = blockIdx.x * blockDim.x + threadIdx.x;
  if (i >= n8) return;
  const float* src = W + (size_t)i * 8;
  f32x4 f0 = *(const f32x4*)src;
  f32x4 f1 = *(const f32x4*)(src + 4);
  *(s16x8*)(Wb + (size_t)i * 8) = pack8(f0, f1);
}

template<bool USE_WB>
__global__ __launch_bounds__(512, 4) void fused_kernel(
    const float* __restrict__ x, const short* __restrict__ Wb,
    const float* __restrict__ Wf, const float* __restrict__ bias,
    const float* __restrict__ scw, const int* __restrict__ mapping,
    float* __restrict__ out, int num_words)
{
  __shared__ short Abuf[2 * ROWS * BK];   // 16 KB, XOR-swizzled, double-buffered
  __shared__ float s_lds[ROWS];           // attention logits

  const int tid = threadIdx.x;
  const int tile = blockIdx.x;
  const int w0 = tile * WPB;
  const int wlast = min(w0 + WPB - 1, num_words - 1);
  const int r0 = mapping[2 * w0];
  const int r1 = mapping[2 * wlast + 1];
  const int nrows = min(r1 - r0, ROWS);

  // --- staging geometry: thread -> (row, 8-float slot) of a 64x64 chunk ---
  const int srow = tid >> 3;          // 0..63
  const int sslot = tid & 7;          // 0..7
  const bool sok = srow < nrows;
  const float* xs = x + (size_t)(r0 + srow) * HID + sslot * 8;
  char* wsw = (char*)Abuf + srow * 128 + ((sslot * 16) ^ ((srow & 7) << 4));

  f32x4 sr0, sr1;

  #define ISSUE(CH) do {                                           \
      if (sok) { const float* p_ = xs + (CH) * BK;                 \
        sr0 = *(const f32x4*)p_; sr1 = *(const f32x4*)(p_ + 4); }  \
      else { sr0 = (f32x4){0,0,0,0}; sr1 = (f32x4){0,0,0,0}; } } while(0)

  #define CVTW(BUFI) do {                                          \
      *(s16x8*)(wsw + (BUFI) * (ROWS * BK * 2)) = pack8(sr0, sr1); } while(0)

  ISSUE(0);
  if (tid < ROWS) s_lds[tid] = 0.0f;

  // --- MFMA fragment geometry ---
  const int lane = tid & 63;
  const int wave = tid >> 6;          // 0..7, owns 96-col strip
  const int l15 = lane & 15;
  const int lk  = lane >> 4;          // 0..3
  const int c0  = wave * 96;
  const char* abase = (const char*)Abuf + l15 * 128;
  const int col0 = (lk * 16) ^ ((l15 & 7) << 4);   // kk=0 16B slot (swizzled)
  const int col1 = col0 ^ 64;                      // kk=32 slot

  const short* Bb = Wb + (size_t)(c0 + l15) * HID + lk * 8;
  const float* Bf = Wf + (size_t)(c0 + l15) * HID + lk * 8;

  f32x4 acc[4][6];
  #pragma unroll
  for (int m = 0; m < 4; ++m)
    #pragma unroll
    for (int n = 0; n < 6; ++n) acc[m][n] = (f32x4){0,0,0,0};

  CVTW(0);
  __syncthreads();

  auto gemm_chunk = [&](int bufi, int ch) {
    const char* ab = abase + bufi * (ROWS * BK * 2);
    #pragma unroll
    for (int kk = 0; kk < 2; ++kk) {
      s16x8 a[4], b[6];
      #pragma unroll
      for (int m = 0; m < 4; ++m)
        a[m] = *(const s16x8*)(ab + m * (16 * 128) + (kk ? col1 : col0));
      const int kg = ch * BK + kk * 32;
      #pragma unroll
      for (int n = 0; n < 6; ++n) {
        if constexpr (USE_WB) {
          b[n] = *(const s16x8*)(Bb + n * (16 * HID) + kg);
        } else {
          f32x4 g0 = *(const f32x4*)(Bf + n * (16 * HID) + kg);
          f32x4 g1 = *(const f32x4*)(Bf + n * (16 * HID) + kg + 4);
          b[n] = pack8(g0, g1);
        }
      }
      #pragma unroll
      for (int m = 0; m < 4; ++m)
        #pragma unroll
        for (int n = 0; n < 6; ++n)
          acc[m][n] = __builtin_amdgcn_mfma_f32_16x16x32_bf16(a[m], b[n], acc[m][n], 0, 0, 0);
    }
  };

  // --- K loop: 1 barrier per chunk, depth-1 prefetch (issue-early/write-late) ---
  #pragma unroll 2
  for (int ch = 0; ch < NCH; ++ch) {
    if (ch + 1 < NCH) ISSUE(ch + 1);
    gemm_chunk(ch & 1, ch);
    if (ch + 1 < NCH) CVTW((ch + 1) & 1);
    __syncthreads();
  }

  // --- tanh + scorer dot, reduce 16 lanes -> s_lds ---
  float wv[6], bv[6];
  #pragma unroll
  for (int n = 0; n < 6; ++n) {
    int col = c0 + n * 16 + l15;
    wv[n] = scw[col];
    bv[n] = bias[col];
  }
  #pragma unroll
  for (int m = 0; m < 4; ++m) {
    #pragma unroll
    for (int r = 0; r < 4; ++r) {
      float v = 0.0f;
      #pragma unroll
      for (int n = 0; n < 6; ++n)
        v += fast_tanh(acc[m][n][r] + bv[n]) * wv[n];
      v += __shfl_xor(v, 1);
      v += __shfl_xor(v, 2);
      v += __shfl_xor(v, 4);
      v += __shfl_xor(v, 8);
      if (l15 == 0) atomicAdd(&s_lds[m * 16 + lk * 4 + r], v);
    }
  }
  __syncthreads();

  // --- per-word softmax + weighted sum, x re-read fp32 (L3-resident) ---
  const float LOG2E = 1.4426950408889634f;
  for (int wi = wave; wi < WPB; wi += 8) {
    int gw = w0 + wi;
    if (gw >= num_words) break;
    int grs = mapping[2 * gw];
    int lrs = grs - r0;
    int lre = min(mapping[2 * gw + 1] - r0, nrows);
    int cnt = lre - lrs;
    float mmax = -3.0e38f;
    for (int i = 0; i < cnt; ++i) mmax = fmaxf(mmax, s_lds[lrs + i]);
    float denom = 0.0f;
    for (int i = 0; i < cnt; ++i) denom += exp2f((s_lds[lrs + i] - mmax) * LOG2E);
    float rden = (denom > 0.0f) ? (1.0f / denom) : 0.0f;
    float pb[8];
    #pragma unroll
    for (int i = 0; i < 8; ++i)
      pb[i] = (i < cnt) ? exp2f((s_lds[lrs + i] - mmax) * LOG2E) * rden : 0.0f;
    #pragma unroll
    for (int j = 0; j < 3; ++j) {
      int col = j * 256 + lane * 4;
      const float* xb = x + (size_t)grs * HID + col;
      f32x4 o = {0, 0, 0, 0};
      #pragma unroll
      for (int i = 0; i < 8; ++i) {
        if (i < cnt) {
          f32x4 xv = *(const f32x4*)(xb + (size_t)i * HID);
          o[0] += pb[i] * xv[0];
          o[1] += pb[i] * xv[1];
          o[2] += pb[i] * xv[2];
          o[3] += pb[i] * xv[3];
        }
      }
      for (int i = 8; i < cnt; ++i) {   // generality tail (unused for this data)
        float p = exp2f((s_lds[lrs + i] - mmax) * LOG2E) * rden;
        f32x4 xv = *(const f32x4*)(xb + (size_t)i * HID);
        o[0] += p * xv[0];
        o[1] += p * xv[1];
        o[2] += p * xv[2];
        o[3] += p * xv[3];
      }
      *(f32x4*)(out + (size_t)gw * HID + col) = o;
    }
  }
  #undef ISSUE
  #undef CVTW
}

extern "C" void kernel_launch(void* const* d_in, const int* in_sizes, int n_in,
                              void* d_out, int out_size, void* d_ws, size_t ws_size,
                              hipStream_t stream) {
  const float* x    = (const float*)d_in[0];
  const float* W    = (const float*)d_in[1];
  const float* bias = (const float*)d_in[2];
  const float* scw  = (const float*)d_in[3];
  // d_in[4] (scorer bias) shifts every logit equally -> cancels in softmax
  const int* mapping = (const int*)d_in[5];
  float* out = (float*)d_out;

  int num_words = in_sizes[5] / 2;
  int nblocks = (num_words + WPB - 1) / WPB;

  size_t wb_bytes = (size_t)HID * HID * sizeof(short);
  if (ws_size >= wb_bytes) {
    short* Wb = (short*)d_ws;
    int n8 = HID * HID / 8;
    wconv_kernel<<<(n8 + 255) / 256, 256, 0, stream>>>(W, Wb, n8);
    fused_kernel<true><<<nblocks, 512, 0, stream>>>(x, Wb, W, bias, scw, mapping, out, num_words);
  } else {
    fused_kernel<false><<<nblocks, 512, 0, stream>>>(x, nullptr, W, bias, scw, mapping, out, num_words);
  }
}

// Round 5
// 893.482 us; speedup vs baseline: 2.9251x; 2.9251x over previous
//
#include <hip/hip_runtime.h>

#define HID 768
#define WPB 16     // words per tile
#define ROWS 64    // subword rows per tile
#define BK 64      // K-chunk width
#define NCH 12     // 768 / 64 K-chunks

typedef __attribute__((ext_vector_type(4))) float f32x4;
typedef __attribute__((ext_vector_type(8))) short s16x8;
typedef __attribute__((ext_vector_type(4))) short s16x4;

__device__ inline short f2bf(float f) {
  unsigned u = __builtin_bit_cast(unsigned, f);
  u = (u + 0x7fffu + ((u >> 16) & 1u)) >> 16;
  return (short)(unsigned short)u;
}
__device__ inline float fast_tanh(float v) {
  float e = exp2f(v * 2.885390081777927f);   // e^{2v}
  return 1.0f - 2.0f * __builtin_amdgcn_rcpf(e + 1.0f);
}
__device__ inline s16x8 pack8(f32x4 f0, f32x4 f1) {
  s16x8 p;
  p[0]=f2bf(f0[0]); p[1]=f2bf(f0[1]); p[2]=f2bf(f0[2]); p[3]=f2bf(f0[3]);
  p[4]=f2bf(f1[0]); p[5]=f2bf(f1[1]); p[6]=f2bf(f1[2]); p[7]=f2bf(f1[3]);
  return p;
}
__device__ inline s16x4 pack4(f32x4 f) {
  s16x4 p;
  p[0]=f2bf(f[0]); p[1]=f2bf(f[1]); p[2]=f2bf(f[2]); p[3]=f2bf(f[3]);
  return p;
}

// ---- pre-pass: W fp32 -> bf16 in workspace (L2-resident B operand) ----
__global__ void wconv_kernel(const float* __restrict__ W, short* __restrict__ Wb, int n8) {
  int i = blockIdx.x * blockDim.x + threadIdx.x;
  if (i >= n8) return;
  const float* src = W + (size_t)i * 8;
  f32x4 f0 = *(const f32x4*)src;
  f32x4 f1 = *(const f32x4*)(src + 4);
  *(s16x8*)(Wb + (size_t)i * 8) = pack8(f0, f1);
}

template<bool USE_WB>
__global__ __launch_bounds__(1024, 1) void fused_kernel(
    const float* __restrict__ x, const short* __restrict__ Wb,
    const float* __restrict__ Wf, const float* __restrict__ bias,
    const float* __restrict__ scw, const int* __restrict__ mapping,
    float* __restrict__ out, int num_words)
{
  __shared__ short Abuf[2 * ROWS * BK];   // 16 KB, XOR-swizzled, double-buffered
  __shared__ float s_lds[ROWS];           // attention logits

  const int tid = threadIdx.x;
  const int tile = blockIdx.x;
  const int w0 = tile * WPB;
  const int wlast = min(w0 + WPB - 1, num_words - 1);
  const int r0 = mapping[2 * w0];
  const int r1 = mapping[2 * wlast + 1];
  const int nrows = min(r1 - r0, ROWS);

  // --- staging geometry: 1024 threads -> (row 0..63, 4-float slot 0..15) ---
  const int srow = tid >> 4;
  const int sslot = tid & 15;
  const bool sok = srow < nrows;
  const float* xs = x + (size_t)(r0 + srow) * HID + sslot * 4;
  char* wsw = (char*)Abuf + srow * 128 + ((sslot * 8) ^ ((srow & 7) << 4));

  f32x4 pfA, pfB;

  #define ISSUE(PF, CH) do {                                       \
      PF = sok ? *(const f32x4*)(xs + (CH) * BK) : (f32x4){0,0,0,0}; } while(0)

  #define CVTW(PF, BUFI) do {                                      \
      *(s16x4*)(wsw + (BUFI) * (ROWS * BK * 2)) = pack4(PF); } while(0)

  #define BARRIER() do {                                           \
      asm volatile("s_waitcnt lgkmcnt(0)" ::: "memory");           \
      __builtin_amdgcn_s_barrier(); } while(0)

  if (tid < ROWS) s_lds[tid] = 0.0f;

  // --- MFMA fragment geometry: 16 waves x (64 rows x 48 cols) ---
  const int lane = tid & 63;
  const int wave = tid >> 6;          // 0..15, owns 48-col strip
  const int l15 = lane & 15;
  const int lk  = lane >> 4;          // 0..3
  const int c0  = wave * 48;
  const char* abase = (const char*)Abuf + l15 * 128;
  const int col0 = (lk * 16) ^ ((l15 & 7) << 4);   // kk=0 16B slot (swizzled)
  const int col1 = col0 ^ 64;                      // kk=32 slot

  const short* Bb = Wb + (size_t)(c0 + l15) * HID + lk * 8;
  const float* Bf = Wf + (size_t)(c0 + l15) * HID + lk * 8;

  auto loadB = [&](int n, int kg) -> s16x8 {
    if constexpr (USE_WB) {
      return *(const s16x8*)(Bb + n * (16 * HID) + kg);
    } else {
      f32x4 g0 = *(const f32x4*)(Bf + n * (16 * HID) + kg);
      f32x4 g1 = *(const f32x4*)(Bf + n * (16 * HID) + kg + 4);
      return pack8(g0, g1);
    }
  };

  f32x4 acc[4][3];
  #pragma unroll
  for (int m = 0; m < 4; ++m)
    #pragma unroll
    for (int n = 0; n < 3; ++n) acc[m][n] = (f32x4){0,0,0,0};

  // prologue: chunks 0,1 in flight; chunk 0 -> buf0
  ISSUE(pfA, 0);
  ISSUE(pfB, 1);
  CVTW(pfA, 0);
  BARRIER();

  // One phase = one K-chunk. B-loads first, then A-prefetch (stays in flight
  // across the raw barrier - no vmcnt(0) drain), then MFMAs, then staging write.
  #define PHASE(BUFI, CH, DO_I, PF_I, ICH, DO_W, PF_W) do {                 \
    const int kg0 = (CH) * BK, kg1 = kg0 + 32;                              \
    s16x8 b00 = loadB(0, kg0), b01 = loadB(1, kg0), b02 = loadB(2, kg0);    \
    s16x8 b10 = loadB(0, kg1), b11 = loadB(1, kg1), b12 = loadB(2, kg1);    \
    if (DO_I) ISSUE(PF_I, ICH);                                             \
    const char* ab = abase + (BUFI) * (ROWS * BK * 2);                      \
    s16x8 a0, a1, a2, a3;                                                   \
    a0 = *(const s16x8*)(ab + 0 * (16*128) + col0);                         \
    a1 = *(const s16x8*)(ab + 1 * (16*128) + col0);                         \
    a2 = *(const s16x8*)(ab + 2 * (16*128) + col0);                         \
    a3 = *(const s16x8*)(ab + 3 * (16*128) + col0);                         \
    acc[0][0] = __builtin_amdgcn_mfma_f32_16x16x32_bf16(a0, b00, acc[0][0], 0,0,0); \
    acc[0][1] = __builtin_amdgcn_mfma_f32_16x16x32_bf16(a0, b01, acc[0][1], 0,0,0); \
    acc[0][2] = __builtin_amdgcn_mfma_f32_16x16x32_bf16(a0, b02, acc[0][2], 0,0,0); \
    acc[1][0] = __builtin_amdgcn_mfma_f32_16x16x32_bf16(a1, b00, acc[1][0], 0,0,0); \
    acc[1][1] = __builtin_amdgcn_mfma_f32_16x16x32_bf16(a1, b01, acc[1][1], 0,0,0); \
    acc[1][2] = __builtin_amdgcn_mfma_f32_16x16x32_bf16(a1, b02, acc[1][2], 0,0,0); \
    acc[2][0] = __builtin_amdgcn_mfma_f32_16x16x32_bf16(a2, b00, acc[2][0], 0,0,0); \
    acc[2][1] = __builtin_amdgcn_mfma_f32_16x16x32_bf16(a2, b01, acc[2][1], 0,0,0); \
    acc[2][2] = __builtin_amdgcn_mfma_f32_16x16x32_bf16(a2, b02, acc[2][2], 0,0,0); \
    acc[3][0] = __builtin_amdgcn_mfma_f32_16x16x32_bf16(a3, b00, acc[3][0], 0,0,0); \
    acc[3][1] = __builtin_amdgcn_mfma_f32_16x16x32_bf16(a3, b01, acc[3][1], 0,0,0); \
    acc[3][2] = __builtin_amdgcn_mfma_f32_16x16x32_bf16(a3, b02, acc[3][2], 0,0,0); \
    a0 = *(const s16x8*)(ab + 0 * (16*128) + col1);                         \
    a1 = *(const s16x8*)(ab + 1 * (16*128) + col1);                         \
    a2 = *(const s16x8*)(ab + 2 * (16*128) + col1);                         \
    a3 = *(const s16x8*)(ab + 3 * (16*128) + col1);                         \
    acc[0][0] = __builtin_amdgcn_mfma_f32_16x16x32_bf16(a0, b10, acc[0][0], 0,0,0); \
    acc[0][1] = __builtin_amdgcn_mfma_f32_16x16x32_bf16(a0, b11, acc[0][1], 0,0,0); \
    acc[0][2] = __builtin_amdgcn_mfma_f32_16x16x32_bf16(a0, b12, acc[0][2], 0,0,0); \
    acc[1][0] = __builtin_amdgcn_mfma_f32_16x16x32_bf16(a1, b10, acc[1][0], 0,0,0); \
    acc[1][1] = __builtin_amdgcn_mfma_f32_16x16x32_bf16(a1, b11, acc[1][1], 0,0,0); \
    acc[1][2] = __builtin_amdgcn_mfma_f32_16x16x32_bf16(a1, b12, acc[1][2], 0,0,0); \
    acc[2][0] = __builtin_amdgcn_mfma_f32_16x16x32_bf16(a2, b10, acc[2][0], 0,0,0); \
    acc[2][1] = __builtin_amdgcn_mfma_f32_16x16x32_bf16(a2, b11, acc[2][1], 0,0,0); \
    acc[2][2] = __builtin_amdgcn_mfma_f32_16x16x32_bf16(a2, b12, acc[2][2], 0,0,0); \
    acc[3][0] = __builtin_amdgcn_mfma_f32_16x16x32_bf16(a3, b10, acc[3][0], 0,0,0); \
    acc[3][1] = __builtin_amdgcn_mfma_f32_16x16x32_bf16(a3, b11, acc[3][1], 0,0,0); \
    acc[3][2] = __builtin_amdgcn_mfma_f32_16x16x32_bf16(a3, b12, acc[3][2], 0,0,0); \
    if (DO_W) CVTW(PF_W, (BUFI) ^ 1);                                       \
    BARRIER();                                                              \
  } while(0)

  #pragma unroll 1
  for (int ch = 0; ch < NCH; ch += 2) {
    PHASE(0, ch,     ch + 2 < NCH, pfA, ch + 2, true,          pfB);
    PHASE(1, ch + 1, ch + 3 < NCH, pfB, ch + 3, ch + 2 < NCH,  pfA);
  }

  // --- tanh + scorer dot, reduce 16 lanes -> s_lds ---
  float wv[3], bv[3];
  #pragma unroll
  for (int n = 0; n < 3; ++n) {
    int col = c0 + n * 16 + l15;
    wv[n] = scw[col];
    bv[n] = bias[col];
  }
  #pragma unroll
  for (int m = 0; m < 4; ++m) {
    #pragma unroll
    for (int r = 0; r < 4; ++r) {
      float v = 0.0f;
      #pragma unroll
      for (int n = 0; n < 3; ++n)
        v += fast_tanh(acc[m][n][r] + bv[n]) * wv[n];
      v += __shfl_xor(v, 1);
      v += __shfl_xor(v, 2);
      v += __shfl_xor(v, 4);
      v += __shfl_xor(v, 8);
      if (l15 == 0) atomicAdd(&s_lds[m * 16 + lk * 4 + r], v);
    }
  }
  __syncthreads();

  // --- per-word softmax + weighted sum, x re-read fp32 (L2/L3-resident) ---
  const float LOG2E = 1.4426950408889634f;
  int gw = w0 + wave;                  // 16 waves <-> 16 words
  if (wave < WPB && gw < num_words) {
    int grs = mapping[2 * gw];
    int lrs = grs - r0;
    int cnt = min(mapping[2 * gw + 1] - r0, nrows) - lrs;
    float mmax = -3.0e38f;
    for (int i = 0; i < cnt; ++i) mmax = fmaxf(mmax, s_lds[lrs + i]);
    float denom = 0.0f;
    for (int i = 0; i < cnt; ++i) denom += exp2f((s_lds[lrs + i] - mmax) * LOG2E);
    float rden = (denom > 0.0f) ? (1.0f / denom) : 0.0f;
    float pb[8];
    #pragma unroll
    for (int i = 0; i < 8; ++i)
      pb[i] = (i < cnt) ? exp2f((s_lds[lrs + i] - mmax) * LOG2E) * rden : 0.0f;
    #pragma unroll
    for (int j = 0; j < 3; ++j) {
      int col = j * 256 + lane * 4;
      const float* xb = x + (size_t)grs * HID + col;
      f32x4 o = {0, 0, 0, 0};
      #pragma unroll
      for (int i = 0; i < 8; ++i) {
        if (i < cnt) {
          f32x4 xv = *(const f32x4*)(xb + (size_t)i * HID);
          o[0] += pb[i] * xv[0];
          o[1] += pb[i] * xv[1];
          o[2] += pb[i] * xv[2];
          o[3] += pb[i] * xv[3];
        }
      }
      for (int i = 8; i < cnt; ++i) {   // generality tail (unused for this data)
        float p = exp2f((s_lds[lrs + i] - mmax) * LOG2E) * rden;
        f32x4 xv = *(const f32x4*)(xb + (size_t)i * HID);
        o[0] += p * xv[0];
        o[1] += p * xv[1];
        o[2] += p * xv[2];
        o[3] += p * xv[3];
      }
      *(f32x4*)(out + (size_t)gw * HID + col) = o;
    }
  }
  #undef ISSUE
  #undef CVTW
  #undef BARRIER
  #undef PHASE
}

extern "C" void kernel_launch(void* const* d_in, const int* in_sizes, int n_in,
                              void* d_out, int out_size, void* d_ws, size_t ws_size,
                              hipStream_t stream) {
  const float* x    = (const float*)d_in[0];
  const float* W    = (const float*)d_in[1];
  const float* bias = (const float*)d_in[2];
  const float* scw  = (const float*)d_in[3];
  // d_in[4] (scorer bias) shifts every logit equally -> cancels in softmax
  const int* mapping = (const int*)d_in[5];
  float* out = (float*)d_out;

  int num_words = in_sizes[5] / 2;
  int nblocks = (num_words + WPB - 1) / WPB;

  size_t wb_bytes = (size_t)HID * HID * sizeof(short);
  if (ws_size >= wb_bytes) {
    short* Wb = (short*)d_ws;
    int n8 = HID * HID / 8;
    wconv_kernel<<<(n8 + 255) / 256, 256, 0, stream>>>(W, Wb, n8);
    fused_kernel<true><<<nblocks, 1024, 0, stream>>>(x, Wb, W, bias, scw, mapping, out, num_words);
  } else {
    fused_kernel<false><<<nblocks, 1024, 0, stream>>>(x, nullptr, W, bias, scw, mapping, out, num_words);
  }
}

// Round 6
// 858.604 us; speedup vs baseline: 3.0439x; 1.0406x over previous
//
#include <hip/hip_runtime.h>

#define HID 768
#define WPB 24     // words per tile
#define ROWS 96    // subword rows per tile (24 words * avg 4)
#define BK 64      // K-chunk width
#define NCH 12     // 768 / 64 K-chunks

typedef __attribute__((ext_vector_type(4))) float f32x4;
typedef __attribute__((ext_vector_type(8))) short s16x8;
typedef __attribute__((ext_vector_type(4))) short s16x4;

__device__ inline short f2bf(float f) {
  unsigned u = __builtin_bit_cast(unsigned, f);
  u = (u + 0x7fffu + ((u >> 16) & 1u)) >> 16;
  return (short)(unsigned short)u;
}
__device__ inline float fast_tanh(float v) {
  float e = exp2f(v * 2.885390081777927f);   // e^{2v}
  return 1.0f - 2.0f * __builtin_amdgcn_rcpf(e + 1.0f);
}
__device__ inline s16x8 pack8(f32x4 f0, f32x4 f1) {
  s16x8 p;
  p[0]=f2bf(f0[0]); p[1]=f2bf(f0[1]); p[2]=f2bf(f0[2]); p[3]=f2bf(f0[3]);
  p[4]=f2bf(f1[0]); p[5]=f2bf(f1[1]); p[6]=f2bf(f1[2]); p[7]=f2bf(f1[3]);
  return p;
}
__device__ inline s16x4 pack4(f32x4 f) {
  s16x4 p;
  p[0]=f2bf(f[0]); p[1]=f2bf(f[1]); p[2]=f2bf(f[2]); p[3]=f2bf(f[3]);
  return p;
}

// ---- pre-pass: W fp32 -> bf16 in workspace (L2-resident B operand) ----
__global__ void wconv_kernel(const float* __restrict__ W, short* __restrict__ Wb, int n8) {
  int i = blockIdx.x * blockDim.x + threadIdx.x;
  if (i >= n8) return;
  const float* src = W + (size_t)i * 8;
  f32x4 f0 = *(const f32x4*)src;
  f32x4 f1 = *(const f32x4*)(src + 4);
  *(s16x8*)(Wb + (size_t)i * 8) = pack8(f0, f1);
}

template<bool USE_WB>
__global__ __launch_bounds__(512, 2) void fused_kernel(
    const float* __restrict__ x, const short* __restrict__ Wb,
    const float* __restrict__ Wf, const float* __restrict__ bias,
    const float* __restrict__ scw, const int* __restrict__ mapping,
    float* __restrict__ out, int num_words)
{
  __shared__ __align__(16) short Abuf[2 * ROWS * BK];  // 24 KB, swizzled, dbuf
  __shared__ float s_lds[ROWS];                        // attention logits

  const int tid = threadIdx.x;
  const int tile = blockIdx.x;
  const int w0 = tile * WPB;
  const int wlast = min(w0 + WPB - 1, num_words - 1);
  const int r0 = mapping[2 * w0];
  const int r1 = mapping[2 * wlast + 1];
  const int nrows = min(r1 - r0, ROWS);

  // --- staging: 512 threads x 3 slots cover 96 rows x 16 (4-float) slots ---
  int srowv[3], gofsv[3], lofsv[3];
  bool okv[3];
  #pragma unroll
  for (int it = 0; it < 3; ++it) {
    int s = tid + it * 512;
    int row = s >> 4;
    int c4 = s & 15;
    srowv[it] = row;
    okv[it] = row < nrows;
    gofsv[it] = row * HID + c4 * 4;
    lofsv[it] = row * 128 + ((c4 * 8) ^ ((row & 7) << 4));
  }
  f32x4 pf0, pf1, pf2;

  #define ISSUE(CH) do {                                                     \
      pf0 = okv[0] ? *(const f32x4*)(x + (size_t)r0 * HID + gofsv[0] + (CH) * BK) : (f32x4){0,0,0,0}; \
      pf1 = okv[1] ? *(const f32x4*)(x + (size_t)r0 * HID + gofsv[1] + (CH) * BK) : (f32x4){0,0,0,0}; \
      pf2 = okv[2] ? *(const f32x4*)(x + (size_t)r0 * HID + gofsv[2] + (CH) * BK) : (f32x4){0,0,0,0}; \
    } while(0)

  #define CVTW(BUFI) do {                                                    \
      char* bb_ = (char*)Abuf + (BUFI) * (ROWS * BK * 2);                    \
      *(s16x4*)(bb_ + lofsv[0]) = pack4(pf0);                                \
      *(s16x4*)(bb_ + lofsv[1]) = pack4(pf1);                                \
      *(s16x4*)(bb_ + lofsv[2]) = pack4(pf2);                                \
    } while(0)

  #define BARRIER() do {                                                     \
      asm volatile("s_waitcnt lgkmcnt(0)" ::: "memory");                     \
      __builtin_amdgcn_s_barrier(); } while(0)

  if (tid < ROWS) s_lds[tid] = 0.0f;

  // --- MFMA fragment geometry: 8 waves, each 96 rows x 96-col strip ---
  const int lane = tid & 63;
  const int wave = tid >> 6;          // 0..7
  const int l15 = lane & 15;
  const int lk  = lane >> 4;          // 0..3
  const int c0  = wave * 96;
  const char* abase = (const char*)Abuf + l15 * 128;
  const int col0 = (lk * 16) ^ ((l15 & 7) << 4);   // kk=0 16B slot (swizzled)
  const int col1 = col0 ^ 64;                      // kk=32 slot

  const short* Bb = Wb + (size_t)(c0 + l15) * HID + lk * 8;
  const float* Bf = Wf + (size_t)(c0 + l15) * HID + lk * 8;

  auto loadB = [&](int n, int kg) -> s16x8 {
    if constexpr (USE_WB) {
      return *(const s16x8*)(Bb + n * (16 * HID) + kg);
    } else {
      f32x4 g0 = *(const f32x4*)(Bf + n * (16 * HID) + kg);
      f32x4 g1 = *(const f32x4*)(Bf + n * (16 * HID) + kg + 4);
      return pack8(g0, g1);
    }
  };

  f32x4 acc[6][6];
  #pragma unroll
  for (int m = 0; m < 6; ++m)
    #pragma unroll
    for (int n = 0; n < 6; ++n) acc[m][n] = (f32x4){0,0,0,0};

  auto gemm_chunk = [&](int bufi, int ch) {
    const char* ab = abase + bufi * (ROWS * BK * 2);
    #pragma unroll
    for (int kk = 0; kk < 2; ++kk) {
      const int kg = ch * BK + kk * 32;
      s16x8 b[6];
      #pragma unroll
      for (int n = 0; n < 6; ++n) b[n] = loadB(n, kg);
      s16x8 a[6];
      #pragma unroll
      for (int m = 0; m < 6; ++m)
        a[m] = *(const s16x8*)(ab + m * (16 * 128) + (kk ? col1 : col0));
      __builtin_amdgcn_s_setprio(1);
      #pragma unroll
      for (int n = 0; n < 6; ++n)
        #pragma unroll
        for (int m = 0; m < 6; ++m)
          acc[m][n] = __builtin_amdgcn_mfma_f32_16x16x32_bf16(a[m], b[n], acc[m][n], 0, 0, 0);
      __builtin_amdgcn_s_setprio(0);
    }
  };

  // prologue: chunk 0 staged
  ISSUE(0);
  CVTW(0);
  BARRIER();

  // K loop: raw barrier (no vmcnt drain), depth-1 prefetch hidden under MFMAs
  #pragma unroll 1
  for (int ch = 0; ch < NCH; ++ch) {
    const int bufi = ch & 1;
    {
      const char* ab = abase + bufi * (ROWS * BK * 2);
      const int kg = ch * BK;
      // kk = 0
      s16x8 b[6];
      #pragma unroll
      for (int n = 0; n < 6; ++n) b[n] = loadB(n, kg);
      if (ch + 1 < NCH) ISSUE(ch + 1);
      s16x8 a[6];
      #pragma unroll
      for (int m = 0; m < 6; ++m)
        a[m] = *(const s16x8*)(ab + m * (16 * 128) + col0);
      __builtin_amdgcn_s_setprio(1);
      #pragma unroll
      for (int n = 0; n < 6; ++n)
        #pragma unroll
        for (int m = 0; m < 6; ++m)
          acc[m][n] = __builtin_amdgcn_mfma_f32_16x16x32_bf16(a[m], b[n], acc[m][n], 0, 0, 0);
      __builtin_amdgcn_s_setprio(0);
      // kk = 1
      #pragma unroll
      for (int n = 0; n < 6; ++n) b[n] = loadB(n, kg + 32);
      #pragma unroll
      for (int m = 0; m < 6; ++m)
        a[m] = *(const s16x8*)(ab + m * (16 * 128) + col1);
      __builtin_amdgcn_s_setprio(1);
      #pragma unroll
      for (int n = 0; n < 6; ++n)
        #pragma unroll
        for (int m = 0; m < 6; ++m)
          acc[m][n] = __builtin_amdgcn_mfma_f32_16x16x32_bf16(a[m], b[n], acc[m][n], 0, 0, 0);
      __builtin_amdgcn_s_setprio(0);
    }
    if (ch + 1 < NCH) CVTW(bufi ^ 1);
    BARRIER();
  }

  // --- tanh + scorer dot, reduce 16 lanes -> s_lds ---
  float wv[6], bv[6];
  #pragma unroll
  for (int n = 0; n < 6; ++n) {
    int col = c0 + n * 16 + l15;
    wv[n] = scw[col];
    bv[n] = bias[col];
  }
  #pragma unroll
  for (int m = 0; m < 6; ++m) {
    #pragma unroll
    for (int r = 0; r < 4; ++r) {
      float v = 0.0f;
      #pragma unroll
      for (int n = 0; n < 6; ++n)
        v += fast_tanh(acc[m][n][r] + bv[n]) * wv[n];
      v += __shfl_xor(v, 1);
      v += __shfl_xor(v, 2);
      v += __shfl_xor(v, 4);
      v += __shfl_xor(v, 8);
      if (l15 == 0) atomicAdd(&s_lds[m * 16 + lk * 4 + r], v);
    }
  }
  __syncthreads();

  // --- per-word softmax + weighted sum, x re-read fp32 (L2/L3-resident) ---
  const float LOG2E = 1.4426950408889634f;
  for (int wi = wave; wi < WPB; wi += 8) {
    int gw = w0 + wi;
    if (gw >= num_words) break;
    int grs = mapping[2 * gw];
    int lrs = grs - r0;
    int cnt = min(mapping[2 * gw + 1] - r0, nrows) - lrs;
    float mmax = -3.0e38f;
    for (int i = 0; i < cnt; ++i) mmax = fmaxf(mmax, s_lds[lrs + i]);
    float denom = 0.0f;
    for (int i = 0; i < cnt; ++i) denom += exp2f((s_lds[lrs + i] - mmax) * LOG2E);
    float rden = (denom > 0.0f) ? (1.0f / denom) : 0.0f;
    float pb[8];
    #pragma unroll
    for (int i = 0; i < 8; ++i)
      pb[i] = (i < cnt) ? exp2f((s_lds[lrs + i] - mmax) * LOG2E) * rden : 0.0f;
    #pragma unroll
    for (int j = 0; j < 3; ++j) {
      int col = j * 256 + lane * 4;
      const float* xb = x + (size_t)grs * HID + col;
      f32x4 o = {0, 0, 0, 0};
      #pragma unroll
      for (int i = 0; i < 8; ++i) {
        if (i < cnt) {
          f32x4 xv = *(const f32x4*)(xb + (size_t)i * HID);
          o[0] += pb[i] * xv[0];
          o[1] += pb[i] * xv[1];
          o[2] += pb[i] * xv[2];
          o[3] += pb[i] * xv[3];
        }
      }
      for (int i = 8; i < cnt; ++i) {   // generality tail (unused for this data)
        float p = exp2f((s_lds[lrs + i] - mmax) * LOG2E) * rden;
        f32x4 xv = *(const f32x4*)(xb + (size_t)i * HID);
        o[0] += p * xv[0];
        o[1] += p * xv[1];
        o[2] += p * xv[2];
        o[3] += p * xv[3];
      }
      *(f32x4*)(out + (size_t)gw * HID + col) = o;
    }
  }
  #undef ISSUE
  #undef CVTW
  #undef BARRIER
}

extern "C" void kernel_launch(void* const* d_in, const int* in_sizes, int n_in,
                              void* d_out, int out_size, void* d_ws, size_t ws_size,
                              hipStream_t stream) {
  const float* x    = (const float*)d_in[0];
  const float* W    = (const float*)d_in[1];
  const float* bias = (const float*)d_in[2];
  const float* scw  = (const float*)d_in[3];
  // d_in[4] (scorer bias) shifts every logit equally -> cancels in softmax
  const int* mapping = (const int*)d_in[5];
  float* out = (float*)d_out;

  int num_words = in_sizes[5] / 2;
  int nblocks = (num_words + WPB - 1) / WPB;

  size_t wb_bytes = (size_t)HID * HID * sizeof(short);
  if (ws_size >= wb_bytes) {
    short* Wb = (short*)d_ws;
    int n8 = HID * HID / 8;
    wconv_kernel<<<(n8 + 255) / 256, 256, 0, stream>>>(W, Wb, n8);
    fused_kernel<true><<<nblocks, 512, 0, stream>>>(x, Wb, W, bias, scw, mapping, out, num_words);
  } else {
    fused_kernel<false><<<nblocks, 512, 0, stream>>>(x, nullptr, W, bias, scw, mapping, out, num_words);
  }
}

// Round 7
// 667.169 us; speedup vs baseline: 3.9173x; 1.2869x over previous
//
#include <hip/hip_runtime.h>

#define HID 768
#define WPB 24     // words per tile
#define ROWS 96    // subword rows per tile (24 words * avg 4)
#define BK 64      // K-chunk width
#define NCH 12     // 768 / 64 K-chunks

typedef __attribute__((ext_vector_type(4))) float f32x4;
typedef __attribute__((ext_vector_type(8))) short s16x8;
typedef __attribute__((ext_vector_type(4))) short s16x4;

__device__ inline short f2bf(float f) {
  unsigned u = __builtin_bit_cast(unsigned, f);
  u = (u + 0x7fffu + ((u >> 16) & 1u)) >> 16;
  return (short)(unsigned short)u;
}
__device__ inline float fast_tanh(float v) {
  float e = exp2f(v * 2.885390081777927f);   // e^{2v}
  return 1.0f - 2.0f * __builtin_amdgcn_rcpf(e + 1.0f);
}
__device__ inline s16x8 pack8(f32x4 f0, f32x4 f1) {
  s16x8 p;
  p[0]=f2bf(f0[0]); p[1]=f2bf(f0[1]); p[2]=f2bf(f0[2]); p[3]=f2bf(f0[3]);
  p[4]=f2bf(f1[0]); p[5]=f2bf(f1[1]); p[6]=f2bf(f1[2]); p[7]=f2bf(f1[3]);
  return p;
}
__device__ inline s16x4 pack4(f32x4 f) {
  s16x4 p;
  p[0]=f2bf(f[0]); p[1]=f2bf(f[1]); p[2]=f2bf(f[2]); p[3]=f2bf(f[3]);
  return p;
}

// ---- pre-pass: W fp32 -> bf16 in MFMA FRAGMENT ORDER ----
// Fragment (kc, t): k-chunk kc (32 wide), col-tile t (16 wide). 64 lanes x 16B
// stored contiguously (1 KB). Lane l holds W[t*16 + (l&15)][kc*32 + (l>>4)*8 .. +8]
// -> identical per-lane content to the (verified) strided layout, but a wave's
// loadB is now ONE coalesced 1 KB read instead of a 64-way 1536B-stride gather.
__global__ void wconv_kernel(const float* __restrict__ W, short* __restrict__ Wb, int n64) {
  int gid = blockIdx.x * blockDim.x + threadIdx.x;
  if (gid >= n64) return;                  // n64 = 24*48*64 = 73728
  int lane = gid & 63;
  int frag = gid >> 6;
  int kc = frag / 48;                      // 0..23
  int t  = frag - kc * 48;                 // 0..47
  int col = t * 16 + (lane & 15);
  int k0  = kc * 32 + (lane >> 4) * 8;
  const float* src = W + (size_t)col * HID + k0;
  f32x4 f0 = *(const f32x4*)src;
  f32x4 f1 = *(const f32x4*)(src + 4);
  *(s16x8*)(Wb + (size_t)gid * 8) = pack8(f0, f1);
}

template<bool USE_WB>
__global__ __launch_bounds__(512, 2) void fused_kernel(
    const float* __restrict__ x, const short* __restrict__ Wb,
    const float* __restrict__ Wf, const float* __restrict__ bias,
    const float* __restrict__ scw, const int* __restrict__ mapping,
    float* __restrict__ out, int num_words)
{
  __shared__ __align__(16) short Abuf[2 * ROWS * BK];  // 24 KB, swizzled, dbuf
  __shared__ float s_lds[ROWS];                        // attention logits

  const int tid = threadIdx.x;
  const int tile = blockIdx.x;
  const int w0 = tile * WPB;
  const int wlast = min(w0 + WPB - 1, num_words - 1);
  const int r0 = mapping[2 * w0];
  const int r1 = mapping[2 * wlast + 1];
  const int nrows = min(r1 - r0, ROWS);

  // --- staging: 512 threads x 3 slots cover 96 rows x 16 (4-float) slots ---
  int gofsv[3], lofsv[3];
  bool okv[3];
  #pragma unroll
  for (int it = 0; it < 3; ++it) {
    int s = tid + it * 512;
    int row = s >> 4;
    int c4 = s & 15;
    okv[it] = row < nrows;
    gofsv[it] = row * HID + c4 * 4;
    lofsv[it] = row * 128 + ((c4 * 8) ^ ((row & 7) << 4));
  }
  f32x4 pf0, pf1, pf2;

  #define ISSUE(CH) do {                                                     \
      pf0 = okv[0] ? *(const f32x4*)(x + (size_t)r0 * HID + gofsv[0] + (CH) * BK) : (f32x4){0,0,0,0}; \
      pf1 = okv[1] ? *(const f32x4*)(x + (size_t)r0 * HID + gofsv[1] + (CH) * BK) : (f32x4){0,0,0,0}; \
      pf2 = okv[2] ? *(const f32x4*)(x + (size_t)r0 * HID + gofsv[2] + (CH) * BK) : (f32x4){0,0,0,0}; \
    } while(0)

  #define CVTW(BUFI) do {                                                    \
      char* bb_ = (char*)Abuf + (BUFI) * (ROWS * BK * 2);                    \
      *(s16x4*)(bb_ + lofsv[0]) = pack4(pf0);                                \
      *(s16x4*)(bb_ + lofsv[1]) = pack4(pf1);                                \
      *(s16x4*)(bb_ + lofsv[2]) = pack4(pf2);                                \
    } while(0)

  #define BARRIER() do {                                                     \
      asm volatile("s_waitcnt lgkmcnt(0)" ::: "memory");                     \
      __builtin_amdgcn_s_barrier(); } while(0)

  if (tid < ROWS) s_lds[tid] = 0.0f;

  // --- MFMA fragment geometry: 8 waves, each 96 rows x 96-col strip ---
  const int lane = tid & 63;
  const int wave = tid >> 6;          // 0..7
  const int l15 = lane & 15;
  const int lk  = lane >> 4;          // 0..3
  const int c0  = wave * 96;
  const char* abase = (const char*)Abuf + l15 * 128;
  const int col0 = (lk * 16) ^ ((l15 & 7) << 4);   // kk=0 16B slot (swizzled)
  const int col1 = col0 ^ 64;                      // kk=32 slot

  // fragment-ordered B: frag(kc, t) at (kc*48 + t)*512 shorts, lane at +lane*8
  const short* B2 = Wb + (size_t)(wave * 6) * 512 + lane * 8;
  const float* Bf = Wf + (size_t)(c0 + l15) * HID + lk * 8;

  auto loadB = [&](int n, int kc) -> s16x8 {
    if constexpr (USE_WB) {
      return *(const s16x8*)(B2 + (size_t)kc * 24576 + n * 512);
    } else {
      f32x4 g0 = *(const f32x4*)(Bf + n * (16 * HID) + kc * 32);
      f32x4 g1 = *(const f32x4*)(Bf + n * (16 * HID) + kc * 32 + 4);
      return pack8(g0, g1);
    }
  };

  f32x4 acc[6][6];
  #pragma unroll
  for (int m = 0; m < 6; ++m)
    #pragma unroll
    for (int n = 0; n < 6; ++n) acc[m][n] = (f32x4){0,0,0,0};

  // prologue: chunk 0 staged
  ISSUE(0);
  CVTW(0);
  BARRIER();

  // K loop: raw barrier (no vmcnt drain), depth-1 prefetch hidden under MFMAs
  #pragma unroll 1
  for (int ch = 0; ch < NCH; ++ch) {
    const int bufi = ch & 1;
    {
      const char* ab = abase + bufi * (ROWS * BK * 2);
      // kk = 0
      s16x8 b[6];
      #pragma unroll
      for (int n = 0; n < 6; ++n) b[n] = loadB(n, ch * 2);
      if (ch + 1 < NCH) ISSUE(ch + 1);
      s16x8 a[6];
      #pragma unroll
      for (int m = 0; m < 6; ++m)
        a[m] = *(const s16x8*)(ab + m * (16 * 128) + col0);
      __builtin_amdgcn_s_setprio(1);
      #pragma unroll
      for (int n = 0; n < 6; ++n)
        #pragma unroll
        for (int m = 0; m < 6; ++m)
          acc[m][n] = __builtin_amdgcn_mfma_f32_16x16x32_bf16(a[m], b[n], acc[m][n], 0, 0, 0);
      __builtin_amdgcn_s_setprio(0);
      // kk = 1
      #pragma unroll
      for (int n = 0; n < 6; ++n) b[n] = loadB(n, ch * 2 + 1);
      #pragma unroll
      for (int m = 0; m < 6; ++m)
        a[m] = *(const s16x8*)(ab + m * (16 * 128) + col1);
      __builtin_amdgcn_s_setprio(1);
      #pragma unroll
      for (int n = 0; n < 6; ++n)
        #pragma unroll
        for (int m = 0; m < 6; ++m)
          acc[m][n] = __builtin_amdgcn_mfma_f32_16x16x32_bf16(a[m], b[n], acc[m][n], 0, 0, 0);
      __builtin_amdgcn_s_setprio(0);
    }
    if (ch + 1 < NCH) CVTW(bufi ^ 1);
    BARRIER();
  }

  // --- tanh + scorer dot, reduce 16 lanes -> s_lds ---
  float wv[6], bv[6];
  #pragma unroll
  for (int n = 0; n < 6; ++n) {
    int col = c0 + n * 16 + l15;
    wv[n] = scw[col];
    bv[n] = bias[col];
  }
  #pragma unroll
  for (int m = 0; m < 6; ++m) {
    #pragma unroll
    for (int r = 0; r < 4; ++r) {
      float v = 0.0f;
      #pragma unroll
      for (int n = 0; n < 6; ++n)
        v += fast_tanh(acc[m][n][r] + bv[n]) * wv[n];
      v += __shfl_xor(v, 1);
      v += __shfl_xor(v, 2);
      v += __shfl_xor(v, 4);
      v += __shfl_xor(v, 8);
      if (l15 == 0) atomicAdd(&s_lds[m * 16 + lk * 4 + r], v);
    }
  }
  __syncthreads();

  // --- per-word softmax + weighted sum, x re-read fp32 (L2/L3-resident) ---
  const float LOG2E = 1.4426950408889634f;
  for (int wi = wave; wi < WPB; wi += 8) {
    int gw = w0 + wi;
    if (gw >= num_words) break;
    int grs = mapping[2 * gw];
    int lrs = grs - r0;
    int cnt = min(mapping[2 * gw + 1] - r0, nrows) - lrs;
    float mmax = -3.0e38f;
    for (int i = 0; i < cnt; ++i) mmax = fmaxf(mmax, s_lds[lrs + i]);
    float denom = 0.0f;
    for (int i = 0; i < cnt; ++i) denom += exp2f((s_lds[lrs + i] - mmax) * LOG2E);
    float rden = (denom > 0.0f) ? (1.0f / denom) : 0.0f;
    float pb[8];
    #pragma unroll
    for (int i = 0; i < 8; ++i)
      pb[i] = (i < cnt) ? exp2f((s_lds[lrs + i] - mmax) * LOG2E) * rden : 0.0f;
    #pragma unroll
    for (int j = 0; j < 3; ++j) {
      int col = j * 256 + lane * 4;
      const float* xb = x + (size_t)grs * HID + col;
      f32x4 o = {0, 0, 0, 0};
      #pragma unroll
      for (int i = 0; i < 8; ++i) {
        if (i < cnt) {
          f32x4 xv = *(const f32x4*)(xb + (size_t)i * HID);
          o[0] += pb[i] * xv[0];
          o[1] += pb[i] * xv[1];
          o[2] += pb[i] * xv[2];
          o[3] += pb[i] * xv[3];
        }
      }
      for (int i = 8; i < cnt; ++i) {   // generality tail (unused for this data)
        float p = exp2f((s_lds[lrs + i] - mmax) * LOG2E) * rden;
        f32x4 xv = *(const f32x4*)(xb + (size_t)i * HID);
        o[0] += p * xv[0];
        o[1] += p * xv[1];
        o[2] += p * xv[2];
        o[3] += p * xv[3];
      }
      *(f32x4*)(out + (size_t)gw * HID + col) = o;
    }
  }
  #undef ISSUE
  #undef CVTW
  #undef BARRIER
}

extern "C" void kernel_launch(void* const* d_in, const int* in_sizes, int n_in,
                              void* d_out, int out_size, void* d_ws, size_t ws_size,
                              hipStream_t stream) {
  const float* x    = (const float*)d_in[0];
  const float* W    = (const float*)d_in[1];
  const float* bias = (const float*)d_in[2];
  const float* scw  = (const float*)d_in[3];
  // d_in[4] (scorer bias) shifts every logit equally -> cancels in softmax
  const int* mapping = (const int*)d_in[5];
  float* out = (float*)d_out;

  int num_words = in_sizes[5] / 2;
  int nblocks = (num_words + WPB - 1) / WPB;

  size_t wb_bytes = (size_t)HID * HID * sizeof(short);
  if (ws_size >= wb_bytes) {
    short* Wb = (short*)d_ws;
    int n64 = (HID / 32) * (HID / 16) * 64;   // 73728 fragment-lane slots
    wconv_kernel<<<(n64 + 255) / 256, 256, 0, stream>>>(W, Wb, n64);
    fused_kernel<true><<<nblocks, 512, 0, stream>>>(x, Wb, W, bias, scw, mapping, out, num_words);
  } else {
    fused_kernel<false><<<nblocks, 512, 0, stream>>>(x, nullptr, W, bias, scw, mapping, out, num_words);
  }
}

// Round 8
// 655.535 us; speedup vs baseline: 3.9869x; 1.0177x over previous
//
#include <hip/hip_runtime.h>

#define HID 768
#define WPB 16     // words per tile
#define ROWS 64    // subword rows per tile
#define BK 64      // K-chunk width
#define NCH 12     // 768 / 64 K-chunks

typedef __attribute__((ext_vector_type(4))) float f32x4;
typedef __attribute__((ext_vector_type(8))) short s16x8;
typedef __attribute__((ext_vector_type(4))) short s16x4;

__device__ inline short f2bf(float f) {
  unsigned u = __builtin_bit_cast(unsigned, f);
  u = (u + 0x7fffu + ((u >> 16) & 1u)) >> 16;
  return (short)(unsigned short)u;
}
__device__ inline float fast_tanh(float v) {
  float e = exp2f(v * 2.885390081777927f);   // e^{2v}
  return 1.0f - 2.0f * __builtin_amdgcn_rcpf(e + 1.0f);
}
__device__ inline s16x8 pack8(f32x4 f0, f32x4 f1) {
  s16x8 p;
  p[0]=f2bf(f0[0]); p[1]=f2bf(f0[1]); p[2]=f2bf(f0[2]); p[3]=f2bf(f0[3]);
  p[4]=f2bf(f1[0]); p[5]=f2bf(f1[1]); p[6]=f2bf(f1[2]); p[7]=f2bf(f1[3]);
  return p;
}
__device__ inline s16x4 pack4(f32x4 f) {
  s16x4 p;
  p[0]=f2bf(f[0]); p[1]=f2bf(f[1]); p[2]=f2bf(f[2]); p[3]=f2bf(f[3]);
  return p;
}

// ---- pre-pass: W fp32 -> bf16 in MFMA FRAGMENT ORDER ----
// Fragment (kc, t): k-chunk kc (32 wide), col-tile t (16 wide). 64 lanes x 16B
// contiguous (1 KB). Lane l holds W[t*16 + (l&15)][kc*32 + (l>>4)*8 .. +8].
// A wave's loadB is ONE coalesced 1 KB read (verified r7: +22%, content
// bit-identical to the strided layout that passes correctness).
__global__ void wconv_kernel(const float* __restrict__ W, short* __restrict__ Wb, int n64) {
  int gid = blockIdx.x * blockDim.x + threadIdx.x;
  if (gid >= n64) return;                  // n64 = 24*48*64 = 73728
  int lane = gid & 63;
  int frag = gid >> 6;
  int kc = frag / 48;                      // 0..23
  int t  = frag - kc * 48;                 // 0..47
  int col = t * 16 + (lane & 15);
  int k0  = kc * 32 + (lane >> 4) * 8;
  const float* src = W + (size_t)col * HID + k0;
  f32x4 f0 = *(const f32x4*)src;
  f32x4 f1 = *(const f32x4*)(src + 4);
  *(s16x8*)(Wb + (size_t)gid * 8) = pack8(f0, f1);
}

template<bool USE_WB>
__global__ __launch_bounds__(1024, 1) void fused_kernel(
    const float* __restrict__ x, const short* __restrict__ Wb,
    const float* __restrict__ Wf, const float* __restrict__ bias,
    const float* __restrict__ scw, const int* __restrict__ mapping,
    float* __restrict__ out, int num_words)
{
  __shared__ short Abuf[2 * ROWS * BK];   // 16 KB, XOR-swizzled, double-buffered
  __shared__ float s_lds[ROWS];           // attention logits

  const int tid = threadIdx.x;
  const int tile = blockIdx.x;
  const int w0 = tile * WPB;
  const int wlast = min(w0 + WPB - 1, num_words - 1);
  const int r0 = mapping[2 * w0];
  const int r1 = mapping[2 * wlast + 1];
  const int nrows = min(r1 - r0, ROWS);

  // --- staging: 1024 threads -> (row 0..63, 4-float slot 0..15) ---
  const int srow = tid >> 4;
  const int sslot = tid & 15;
  const bool sok = srow < nrows;
  const float* xs = x + (size_t)(r0 + srow) * HID + sslot * 4;
  char* wsw = (char*)Abuf + srow * 128 + ((sslot * 8) ^ ((srow & 7) << 4));

  f32x4 pfA, pfB;

  #define ISSUE(PF, CH) do {                                       \
      PF = sok ? *(const f32x4*)(xs + (CH) * BK) : (f32x4){0,0,0,0}; } while(0)

  #define CVTW(PF, BUFI) do {                                      \
      *(s16x4*)(wsw + (BUFI) * (ROWS * BK * 2)) = pack4(PF); } while(0)

  #define BARRIER() do {                                           \
      asm volatile("s_waitcnt lgkmcnt(0)" ::: "memory");           \
      __builtin_amdgcn_s_barrier(); } while(0)

  if (tid < ROWS) s_lds[tid] = 0.0f;

  // --- MFMA fragment geometry: 16 waves x (64 rows x 48 cols) ---
  const int lane = tid & 63;
  const int wave = tid >> 6;          // 0..15, owns 48-col strip
  const int l15 = lane & 15;
  const int lk  = lane >> 4;          // 0..3
  const int c0  = wave * 48;
  const char* abase = (const char*)Abuf + l15 * 128;
  const int col0 = (lk * 16) ^ ((l15 & 7) << 4);   // kk=0 16B slot (swizzled)
  const int col1 = col0 ^ 64;                      // kk=32 slot

  // fragment-ordered B: frag(kc, t) at (kc*48 + t)*512 shorts; this wave's
  // col-tiles start at t = wave*3; lane offset +lane*8.
  const short* B2 = Wb + (size_t)(wave * 3) * 512 + lane * 8;
  const float* Bf = Wf + (size_t)(c0 + l15) * HID + lk * 8;

  auto loadB = [&](int n, int kc) -> s16x8 {
    if constexpr (USE_WB) {
      return *(const s16x8*)(B2 + (size_t)kc * 24576 + n * 512);
    } else {
      f32x4 g0 = *(const f32x4*)(Bf + n * (16 * HID) + kc * 32);
      f32x4 g1 = *(const f32x4*)(Bf + n * (16 * HID) + kc * 32 + 4);
      return pack8(g0, g1);
    }
  };

  f32x4 acc[4][3];
  #pragma unroll
  for (int m = 0; m < 4; ++m)
    #pragma unroll
    for (int n = 0; n < 3; ++n) acc[m][n] = (f32x4){0,0,0,0};

  // prologue: chunks 0,1 in flight; chunk 0 -> buf0
  ISSUE(pfA, 0);
  ISSUE(pfB, 1);
  CVTW(pfA, 0);
  BARRIER();

  // One phase = one K-chunk. B loads first (coalesced 1KB), then A-prefetch
  // (stays in flight across the raw barrier), then MFMAs, then staging write.
  #define PHASE(BUFI, CH, DO_I, PF_I, ICH, DO_W, PF_W) do {                 \
    s16x8 b0[3], b1[3];                                                     \
    _Pragma("unroll")                                                       \
    for (int n = 0; n < 3; ++n) b0[n] = loadB(n, (CH) * 2);                 \
    _Pragma("unroll")                                                       \
    for (int n = 0; n < 3; ++n) b1[n] = loadB(n, (CH) * 2 + 1);             \
    if (DO_I) ISSUE(PF_I, ICH);                                             \
    const char* ab = abase + (BUFI) * (ROWS * BK * 2);                      \
    s16x8 a0, a1, a2, a3;                                                   \
    a0 = *(const s16x8*)(ab + 0 * (16*128) + col0);                         \
    a1 = *(const s16x8*)(ab + 1 * (16*128) + col0);                         \
    a2 = *(const s16x8*)(ab + 2 * (16*128) + col0);                         \
    a3 = *(const s16x8*)(ab + 3 * (16*128) + col0);                         \
    __builtin_amdgcn_s_setprio(1);                                          \
    _Pragma("unroll")                                                       \
    for (int n = 0; n < 3; ++n) {                                           \
      acc[0][n] = __builtin_amdgcn_mfma_f32_16x16x32_bf16(a0, b0[n], acc[0][n], 0,0,0); \
      acc[1][n] = __builtin_amdgcn_mfma_f32_16x16x32_bf16(a1, b0[n], acc[1][n], 0,0,0); \
      acc[2][n] = __builtin_amdgcn_mfma_f32_16x16x32_bf16(a2, b0[n], acc[2][n], 0,0,0); \
      acc[3][n] = __builtin_amdgcn_mfma_f32_16x16x32_bf16(a3, b0[n], acc[3][n], 0,0,0); \
    }                                                                       \
    __builtin_amdgcn_s_setprio(0);                                          \
    a0 = *(const s16x8*)(ab + 0 * (16*128) + col1);                         \
    a1 = *(const s16x8*)(ab + 1 * (16*128) + col1);                         \
    a2 = *(const s16x8*)(ab + 2 * (16*128) + col1);                         \
    a3 = *(const s16x8*)(ab + 3 * (16*128) + col1);                         \
    __builtin_amdgcn_s_setprio(1);                                          \
    _Pragma("unroll")                                                       \
    for (int n = 0; n < 3; ++n) {                                           \
      acc[0][n] = __builtin_amdgcn_mfma_f32_16x16x32_bf16(a0, b1[n], acc[0][n], 0,0,0); \
      acc[1][n] = __builtin_amdgcn_mfma_f32_16x16x32_bf16(a1, b1[n], acc[1][n], 0,0,0); \
      acc[2][n] = __builtin_amdgcn_mfma_f32_16x16x32_bf16(a2, b1[n], acc[2][n], 0,0,0); \
      acc[3][n] = __builtin_amdgcn_mfma_f32_16x16x32_bf16(a3, b1[n], acc[3][n], 0,0,0); \
    }                                                                       \
    __builtin_amdgcn_s_setprio(0);                                          \
    if (DO_W) CVTW(PF_W, (BUFI) ^ 1);                                       \
    BARRIER();                                                              \
  } while(0)

  #pragma unroll 1
  for (int ch = 0; ch < NCH; ch += 2) {
    PHASE(0, ch,     ch + 2 < NCH, pfA, ch + 2, true,          pfB);
    PHASE(1, ch + 1, ch + 3 < NCH, pfB, ch + 3, ch + 2 < NCH,  pfA);
  }

  // --- tanh + scorer dot, reduce 16 lanes -> s_lds ---
  float wv[3], bv[3];
  #pragma unroll
  for (int n = 0; n < 3; ++n) {
    int col = c0 + n * 16 + l15;
    wv[n] = scw[col];
    bv[n] = bias[col];
  }
  #pragma unroll
  for (int m = 0; m < 4; ++m) {
    #pragma unroll
    for (int r = 0; r < 4; ++r) {
      float v = 0.0f;
      #pragma unroll
      for (int n = 0; n < 3; ++n)
        v += fast_tanh(acc[m][n][r] + bv[n]) * wv[n];
      v += __shfl_xor(v, 1);
      v += __shfl_xor(v, 2);
      v += __shfl_xor(v, 4);
      v += __shfl_xor(v, 8);
      if (l15 == 0) atomicAdd(&s_lds[m * 16 + lk * 4 + r], v);
    }
  }
  __syncthreads();

  // --- per-word softmax + weighted sum, x re-read fp32 (L2/L3-resident) ---
  const float LOG2E = 1.4426950408889634f;
  int gw = w0 + wave;                  // 16 waves <-> 16 words
  if (wave < WPB && gw < num_words) {
    int grs = mapping[2 * gw];
    int lrs = grs - r0;
    int cnt = min(mapping[2 * gw + 1] - r0, nrows) - lrs;
    float mmax = -3.0e38f;
    for (int i = 0; i < cnt; ++i) mmax = fmaxf(mmax, s_lds[lrs + i]);
    float denom = 0.0f;
    for (int i = 0; i < cnt; ++i) denom += exp2f((s_lds[lrs + i] - mmax) * LOG2E);
    float rden = (denom > 0.0f) ? (1.0f / denom) : 0.0f;
    float pb[8];
    #pragma unroll
    for (int i = 0; i < 8; ++i)
      pb[i] = (i < cnt) ? exp2f((s_lds[lrs + i] - mmax) * LOG2E) * rden : 0.0f;
    #pragma unroll
    for (int j = 0; j < 3; ++j) {
      int col = j * 256 + lane * 4;
      const float* xb = x + (size_t)grs * HID + col;
      f32x4 o = {0, 0, 0, 0};
      #pragma unroll
      for (int i = 0; i < 8; ++i) {
        if (i < cnt) {
          f32x4 xv = *(const f32x4*)(xb + (size_t)i * HID);
          o[0] += pb[i] * xv[0];
          o[1] += pb[i] * xv[1];
          o[2] += pb[i] * xv[2];
          o[3] += pb[i] * xv[3];
        }
      }
      for (int i = 8; i < cnt; ++i) {   // generality tail (unused for this data)
        float p = exp2f((s_lds[lrs + i] - mmax) * LOG2E) * rden;
        f32x4 xv = *(const f32x4*)(xb + (size_t)i * HID);
        o[0] += p * xv[0];
        o[1] += p * xv[1];
        o[2] += p * xv[2];
        o[3] += p * xv[3];
      }
      *(f32x4*)(out + (size_t)gw * HID + col) = o;
    }
  }
  #undef ISSUE
  #undef CVTW
  #undef BARRIER
  #undef PHASE
}

extern "C" void kernel_launch(void* const* d_in, const int* in_sizes, int n_in,
                              void* d_out, int out_size, void* d_ws, size_t ws_size,
                              hipStream_t stream) {
  const float* x    = (const float*)d_in[0];
  const float* W    = (const float*)d_in[1];
  const float* bias = (const float*)d_in[2];
  const float* scw  = (const float*)d_in[3];
  // d_in[4] (scorer bias) shifts every logit equally -> cancels in softmax
  const int* mapping = (const int*)d_in[5];
  float* out = (float*)d_out;

  int num_words = in_sizes[5] / 2;
  int nblocks = (num_words + WPB - 1) / WPB;

  size_t wb_bytes = (size_t)HID * HID * sizeof(short);
  if (ws_size >= wb_bytes) {
    short* Wb = (short*)d_ws;
    int n64 = (HID / 32) * (HID / 16) * 64;   // 73728 fragment-lane slots
    wconv_kernel<<<(n64 + 255) / 256, 256, 0, stream>>>(W, Wb, n64);
    fused_kernel<true><<<nblocks, 1024, 0, stream>>>(x, Wb, W, bias, scw, mapping, out, num_words);
  } else {
    fused_kernel<false><<<nblocks, 1024, 0, stream>>>(x, nullptr, W, bias, scw, mapping, out, num_words);
  }
}

// Round 9
// 621.097 us; speedup vs baseline: 4.2079x; 1.0554x over previous
//
#include <hip/hip_runtime.h>

#define HID 768
#define WPB 16     // words per tile
#define ROWS 64    // subword rows per tile
#define BK 64      // K-chunk width
#define NCH 12     // 768 / 64 K-chunks

typedef __attribute__((ext_vector_type(4))) float f32x4;
typedef __attribute__((ext_vector_type(8))) short s16x8;
typedef __attribute__((ext_vector_type(4))) short s16x4;

__device__ inline short f2bf(float f) {
  unsigned u = __builtin_bit_cast(unsigned, f);
  u = (u + 0x7fffu + ((u >> 16) & 1u)) >> 16;
  return (short)(unsigned short)u;
}
__device__ inline float fast_tanh(float v) {
  float e = exp2f(v * 2.885390081777927f);   // e^{2v}
  return 1.0f - 2.0f * __builtin_amdgcn_rcpf(e + 1.0f);
}
__device__ inline s16x8 pack8(f32x4 f0, f32x4 f1) {
  s16x8 p;
  p[0]=f2bf(f0[0]); p[1]=f2bf(f0[1]); p[2]=f2bf(f0[2]); p[3]=f2bf(f0[3]);
  p[4]=f2bf(f1[0]); p[5]=f2bf(f1[1]); p[6]=f2bf(f1[2]); p[7]=f2bf(f1[3]);
  return p;
}
__device__ inline s16x4 pack4(f32x4 f) {
  s16x4 p;
  p[0]=f2bf(f[0]); p[1]=f2bf(f[1]); p[2]=f2bf(f[2]); p[3]=f2bf(f[3]);
  return p;
}

// ---- pre-pass: W fp32 -> bf16 in MFMA FRAGMENT ORDER (verified r7/r8) ----
// Fragment (kc, t): k-chunk kc (32 wide), col-tile t (16 wide). 64 lanes x 16B
// contiguous (1 KB). Lane l holds W[t*16 + (l&15)][kc*32 + (l>>4)*8 .. +8].
__global__ void wconv_kernel(const float* __restrict__ W, short* __restrict__ Wb, int n64) {
  int gid = blockIdx.x * blockDim.x + threadIdx.x;
  if (gid >= n64) return;                  // n64 = 24*48*64 = 73728
  int lane = gid & 63;
  int frag = gid >> 6;
  int kc = frag / 48;                      // 0..23
  int t  = frag - kc * 48;                 // 0..47
  int col = t * 16 + (lane & 15);
  int k0  = kc * 32 + (lane >> 4) * 8;
  const float* src = W + (size_t)col * HID + k0;
  f32x4 f0 = *(const f32x4*)src;
  f32x4 f1 = *(const f32x4*)(src + 4);
  *(s16x8*)(Wb + (size_t)gid * 8) = pack8(f0, f1);
}

template<bool USE_WB>
__global__ __launch_bounds__(1024, 1) void fused_kernel(
    const float* __restrict__ x, const short* __restrict__ Wb,
    const float* __restrict__ Wf, const float* __restrict__ bias,
    const float* __restrict__ scw, const int* __restrict__ mapping,
    float* __restrict__ out, int num_words)
{
  __shared__ short Abuf[2 * ROWS * BK];   // 16 KB, XOR-swizzled, double-buffered
  __shared__ float s_lds[ROWS];           // attention logits

  const int tid = threadIdx.x;
  const int tile = blockIdx.x;
  const int w0 = tile * WPB;
  const int wlast = min(w0 + WPB - 1, num_words - 1);
  const int r0 = mapping[2 * w0];
  const int r1 = mapping[2 * wlast + 1];
  const int nrows = min(r1 - r0, ROWS);

  // --- staging: 1024 threads -> (row 0..63, 4-float slot 0..15) ---
  const int srow = tid >> 4;
  const int sslot = tid & 15;
  const bool sok = srow < nrows;
  const float* xs = x + (size_t)(r0 + srow) * HID + sslot * 4;
  char* wsw = (char*)Abuf + srow * 128 + ((sslot * 8) ^ ((srow & 7) << 4));

  f32x4 pfA, pfB;

  #define ISSUE(PF, CH) do {                                       \
      PF = sok ? *(const f32x4*)(xs + (CH) * BK) : (f32x4){0,0,0,0}; } while(0)

  #define CVTW(PF, BUFI) do {                                      \
      *(s16x4*)(wsw + (BUFI) * (ROWS * BK * 2)) = pack4(PF); } while(0)

  #define BARRIER() do {                                           \
      asm volatile("s_waitcnt lgkmcnt(0)" ::: "memory");           \
      __builtin_amdgcn_s_barrier(); } while(0)

  if (tid < ROWS) s_lds[tid] = 0.0f;

  // --- MFMA fragment geometry: 16 waves x (64 rows x 48 cols) ---
  const int lane = tid & 63;
  const int wave = tid >> 6;          // 0..15, owns 48-col strip
  const int l15 = lane & 15;
  const int lk  = lane >> 4;          // 0..3
  const int c0  = wave * 48;
  const char* abase = (const char*)Abuf + l15 * 128;
  const int col0 = (lk * 16) ^ ((l15 & 7) << 4);   // kk=0 16B slot (swizzled)
  const int col1 = col0 ^ 64;                      // kk=32 slot

  // fragment-ordered B: frag(kc, t) at (kc*48 + t)*512 shorts; this wave's
  // col-tiles start at t = wave*3; lane offset +lane*8.
  const short* B2 = Wb + (size_t)(wave * 3) * 512 + lane * 8;
  const float* Bf = Wf + (size_t)(c0 + l15) * HID + lk * 8;

  auto loadB = [&](int n, int kc) -> s16x8 {   // kc = 32-wide chunk idx, 0..23
    if constexpr (USE_WB) {
      return *(const s16x8*)(B2 + (size_t)kc * 24576 + n * 512);
    } else {
      f32x4 g0 = *(const f32x4*)(Bf + n * (16 * HID) + kc * 32);
      f32x4 g1 = *(const f32x4*)(Bf + n * (16 * HID) + kc * 32 + 4);
      return pack8(g0, g1);
    }
  };

  f32x4 acc[4][3];
  #pragma unroll
  for (int m = 0; m < 4; ++m)
    #pragma unroll
    for (int n = 0; n < 3; ++n) acc[m][n] = (f32x4){0,0,0,0};

  // B pipeline registers: bE holds the even kk-half (t=2C), bO the odd (t=2C+1).
  // Each is LOADED one kk-phase before use -> the compiler emits counted vmcnt
  // waits, and loads stay in flight across the raw barrier (T3+T4).
  s16x8 bE[3], bO[3];

  // prologue: A chunks 0,1 in flight; chunk 0 staged; B(t=0) in flight
  ISSUE(pfA, 0);
  ISSUE(pfB, 1);
  #pragma unroll
  for (int n = 0; n < 3; ++n) bE[n] = loadB(n, 0);
  CVTW(pfA, 0);
  BARRIER();

  // One CHUNK = two kk-phases. Per kk-phase: issue next B set, MFMA current.
  // A: ISSUE(chunk C+2) at top, CVTW(chunk C+1) at bottom (2-phase in flight).
  #define CHUNK(C, PFI, ICH, PFW) do {                                       \
    const int bufi = (C) & 1;                                                \
    const char* ab = abase + bufi * (ROWS * BK * 2);                         \
    /* kk=0: prefetch bO(t=2C+1), compute with bE(t=2C) */                   \
    _Pragma("unroll")                                                        \
    for (int n = 0; n < 3; ++n) bO[n] = loadB(n, (C) * 2 + 1);               \
    ISSUE(PFI, (ICH) < NCH ? (ICH) : NCH - 1);                               \
    {                                                                        \
      s16x8 a0 = *(const s16x8*)(ab + 0 * (16*128) + col0);                  \
      s16x8 a1 = *(const s16x8*)(ab + 1 * (16*128) + col0);                  \
      s16x8 a2 = *(const s16x8*)(ab + 2 * (16*128) + col0);                  \
      s16x8 a3 = *(const s16x8*)(ab + 3 * (16*128) + col0);                  \
      __builtin_amdgcn_s_setprio(1);                                         \
      _Pragma("unroll")                                                      \
      for (int n = 0; n < 3; ++n) {                                          \
        acc[0][n] = __builtin_amdgcn_mfma_f32_16x16x32_bf16(a0, bE[n], acc[0][n], 0,0,0); \
        acc[1][n] = __builtin_amdgcn_mfma_f32_16x16x32_bf16(a1, bE[n], acc[1][n], 0,0,0); \
        acc[2][n] = __builtin_amdgcn_mfma_f32_16x16x32_bf16(a2, bE[n], acc[2][n], 0,0,0); \
        acc[3][n] = __builtin_amdgcn_mfma_f32_16x16x32_bf16(a3, bE[n], acc[3][n], 0,0,0); \
      }                                                                      \
      __builtin_amdgcn_s_setprio(0);                                         \
    }                                                                        \
    /* kk=1: prefetch bE(t=2C+2, clamped), compute with bO(t=2C+1) */        \
    {                                                                        \
      const int tn = (C) * 2 + 2;                                            \
      _Pragma("unroll")                                                      \
      for (int n = 0; n < 3; ++n) bE[n] = loadB(n, tn < 24 ? tn : 23);       \
      s16x8 a0 = *(const s16x8*)(ab + 0 * (16*128) + col1);                  \
      s16x8 a1 = *(const s16x8*)(ab + 1 * (16*128) + col1);                  \
      s16x8 a2 = *(const s16x8*)(ab + 2 * (16*128) + col1);                  \
      s16x8 a3 = *(const s16x8*)(ab + 3 * (16*128) + col1);                  \
      __builtin_amdgcn_s_setprio(1);                                         \
      _Pragma("unroll")                                                      \
      for (int n = 0; n < 3; ++n) {                                          \
        acc[0][n] = __builtin_amdgcn_mfma_f32_16x16x32_bf16(a0, bO[n], acc[0][n], 0,0,0); \
        acc[1][n] = __builtin_amdgcn_mfma_f32_16x16x32_bf16(a1, bO[n], acc[1][n], 0,0,0); \
        acc[2][n] = __builtin_amdgcn_mfma_f32_16x16x32_bf16(a2, bO[n], acc[2][n], 0,0,0); \
        acc[3][n] = __builtin_amdgcn_mfma_f32_16x16x32_bf16(a3, bO[n], acc[3][n], 0,0,0); \
      }                                                                      \
      __builtin_amdgcn_s_setprio(0);                                         \
    }                                                                        \
    if ((C) + 1 < NCH) CVTW(PFW, bufi ^ 1);                                  \
    BARRIER();                                                               \
  } while(0)

  #pragma unroll 1
  for (int ch = 0; ch < NCH; ch += 2) {
    CHUNK(ch,     pfA, ch + 2, pfB);
    CHUNK(ch + 1, pfB, ch + 3, pfA);
  }

  // --- tanh + scorer dot, reduce 16 lanes -> s_lds ---
  float wv[3], bv[3];
  #pragma unroll
  for (int n = 0; n < 3; ++n) {
    int col = c0 + n * 16 + l15;
    wv[n] = scw[col];
    bv[n] = bias[col];
  }
  #pragma unroll
  for (int m = 0; m < 4; ++m) {
    #pragma unroll
    for (int r = 0; r < 4; ++r) {
      float v = 0.0f;
      #pragma unroll
      for (int n = 0; n < 3; ++n)
        v += fast_tanh(acc[m][n][r] + bv[n]) * wv[n];
      v += __shfl_xor(v, 1);
      v += __shfl_xor(v, 2);
      v += __shfl_xor(v, 4);
      v += __shfl_xor(v, 8);
      if (l15 == 0) atomicAdd(&s_lds[m * 16 + lk * 4 + r], v);
    }
  }
  __syncthreads();

  // --- per-word softmax + weighted sum, x re-read fp32 (L2/L3-resident) ---
  const float LOG2E = 1.4426950408889634f;
  int gw = w0 + wave;                  // 16 waves <-> 16 words
  if (wave < WPB && gw < num_words) {
    int grs = mapping[2 * gw];
    int lrs = grs - r0;
    int cnt = min(mapping[2 * gw + 1] - r0, nrows) - lrs;
    float mmax = -3.0e38f;
    for (int i = 0; i < cnt; ++i) mmax = fmaxf(mmax, s_lds[lrs + i]);
    float denom = 0.0f;
    for (int i = 0; i < cnt; ++i) denom += exp2f((s_lds[lrs + i] - mmax) * LOG2E);
    float rden = (denom > 0.0f) ? (1.0f / denom) : 0.0f;
    float pb[8];
    #pragma unroll
    for (int i = 0; i < 8; ++i)
      pb[i] = (i < cnt) ? exp2f((s_lds[lrs + i] - mmax) * LOG2E) * rden : 0.0f;
    #pragma unroll
    for (int j = 0; j < 3; ++j) {
      int col = j * 256 + lane * 4;
      const float* xb = x + (size_t)grs * HID + col;
      f32x4 o = {0, 0, 0, 0};
      #pragma unroll
      for (int i = 0; i < 8; ++i) {
        if (i < cnt) {
          f32x4 xv = *(const f32x4*)(xb + (size_t)i * HID);
          o[0] += pb[i] * xv[0];
          o[1] += pb[i] * xv[1];
          o[2] += pb[i] * xv[2];
          o[3] += pb[i] * xv[3];
        }
      }
      for (int i = 8; i < cnt; ++i) {   // generality tail (unused for this data)
        float p = exp2f((s_lds[lrs + i] - mmax) * LOG2E) * rden;
        f32x4 xv = *(const f32x4*)(xb + (size_t)i * HID);
        o[0] += p * xv[0];
        o[1] += p * xv[1];
        o[2] += p * xv[2];
        o[3] += p * xv[3];
      }
      *(f32x4*)(out + (size_t)gw * HID + col) = o;
    }
  }
  #undef ISSUE
  #undef CVTW
  #undef BARRIER
  #undef CHUNK
}

extern "C" void kernel_launch(void* const* d_in, const int* in_sizes, int n_in,
                              void* d_out, int out_size, void* d_ws, size_t ws_size,
                              hipStream_t stream) {
  const float* x    = (const float*)d_in[0];
  const float* W    = (const float*)d_in[1];
  const float* bias = (const float*)d_in[2];
  const float* scw  = (const float*)d_in[3];
  // d_in[4] (scorer bias) shifts every logit equally -> cancels in softmax
  const int* mapping = (const int*)d_in[5];
  float* out = (float*)d_out;

  int num_words = in_sizes[5] / 2;
  int nblocks = (num_words + WPB - 1) / WPB;

  size_t wb_bytes = (size_t)HID * HID * sizeof(short);
  if (ws_size >= wb_bytes) {
    short* Wb = (short*)d_ws;
    int n64 = (HID / 32) * (HID / 16) * 64;   // 73728 fragment-lane slots
    wconv_kernel<<<(n64 + 255) / 256, 256, 0, stream>>>(W, Wb, n64);
    fused_kernel<true><<<nblocks, 1024, 0, stream>>>(x, Wb, W, bias, scw, mapping, out, num_words);
  } else {
    fused_kernel<false><<<nblocks, 1024, 0, stream>>>(x, nullptr, W, bias, scw, mapping, out, num_words);
  }
}